// Round 5
// baseline (2092.736 us; speedup 1.0000x reference)
//
#include <hip/hip_runtime.h>
#include <math.h>

#define NLAY 8
#define BB 4
#define LL 512
#define DDIM 512
#define HH 16
#define KHD 32
#define FFD 2048
#define MMD 512
#define NDB 14
#define QKS 1536
#define SCALEF 0.17677669529663687f

typedef unsigned short u16;
typedef unsigned int u32;
typedef __attribute__((ext_vector_type(8))) short bf16x8;
typedef __attribute__((ext_vector_type(4))) float f32x4;

__device__ __forceinline__ u16 f2bf(float f) {
  unsigned u = __builtin_bit_cast(unsigned, f);
  u = (u + 0x7fffu + ((u >> 16) & 1u)) >> 16;
  return (u16)u;
}
__device__ __forceinline__ float bf2f(u16 v) {
  unsigned u = ((unsigned)v) << 16;
  return __builtin_bit_cast(float, u);
}
__device__ __forceinline__ float wredSum(float v) {
#pragma unroll
  for (int o = 32; o > 0; o >>= 1) v += __shfl_down(v, o);
  return v;
}
__device__ __forceinline__ void gload_lds16(const u16* g, u16* l) {
  __builtin_amdgcn_global_load_lds((const __attribute__((address_space(1))) void*)g,
                                   (__attribute__((address_space(3))) void*)l, 16, 0, 0);
}

// ---------------- bucketize -> uint8 ----------------
__global__ void bucketize_kernel(const float* __restrict__ dist, unsigned char* __restrict__ didx, int n) {
  int i = blockIdx.x * 256 + threadIdx.x;
  if (i >= n) return;
  float d = dist[i];
  int c = 0;
#pragma unroll
  for (int t = 1; t <= NDB; ++t) c += (10.0f * (float)t < d) ? 1 : 0;
  didx[i] = (unsigned char)(c > (NDB - 1) ? (NDB - 1) : c);
}

// ---------------- h = cell_emb[cell_types] (f32 + bf16) ----------------
__global__ void embed_kernel(const int* __restrict__ ct, const float* __restrict__ emb,
                             float* __restrict__ h, u16* __restrict__ hbf, int n) {
  int i = blockIdx.x * 256 + threadIdx.x;
  if (i >= n) return;
  int bl = i >> 9, d = i & 511;
  float v = emb[ct[bl] * DDIM + d];
  h[i] = v;
  hbf[i] = f2bf(v);
}

// ---------------- Vsum, EkrS ----------------
__global__ void prep_kernel(const float* __restrict__ Vqk, const float* __restrict__ Vqr,
                            const float* __restrict__ Vkr, const float* __restrict__ Kkr,
                            float* __restrict__ Vsum, float* __restrict__ EkrS) {
  int tid = threadIdx.x;
  if (tid < NDB * KHD) Vsum[tid] = Vqk[tid] + Vqr[tid] + Vkr[tid];
  if (tid < NDB) {
    float s = 0.f;
    for (int kk = 0; kk < KHD; ++kk) s += Kkr[tid * KHD + kk];
    EkrS[tid] = s;
  }
}

// ---------------- packed qkv bias [NLAY][1536] ----------------
__global__ void biaspack_kernel(const float* __restrict__ bq, const float* __restrict__ bk,
                                const float* __restrict__ bv, float* __restrict__ bqkv) {
  int i = blockIdx.x * 256 + threadIdx.x;
  if (i >= NLAY * QKS) return;
  int lay = i / QKS, c = i % QKS;
  float v;
  if (c < 512) v = bq[lay * DDIM + c];
  else if (c < 1024) v = bk[lay * DDIM + c - 512];
  else v = bv[lay * DDIM + c - 1024];
  bqkv[i] = v;
}

// ---------------- per-layer weight transpose+convert: src f32 [K,N] -> dst bf16 [N,K] ----------------
__device__ __forceinline__ void wtconv_tile(const float* __restrict__ src, u16* __restrict__ dst,
                                            int K, int N, int tn, int tk) {
  __shared__ float tl[64][65];
  const int t = threadIdx.x;
#pragma unroll
  for (int p = 0; p < 4; ++p) {
    int k = tk * 64 + p * 16 + (t >> 4);
    int n = tn * 64 + (t & 15) * 4;
    float4 v = *(const float4*)(src + (size_t)k * N + n);
    tl[(t & 15) * 4 + 0][p * 16 + (t >> 4)] = v.x;
    tl[(t & 15) * 4 + 1][p * 16 + (t >> 4)] = v.y;
    tl[(t & 15) * 4 + 2][p * 16 + (t >> 4)] = v.z;
    tl[(t & 15) * 4 + 3][p * 16 + (t >> 4)] = v.w;
  }
  __syncthreads();
  int n = t >> 2, cc = t & 3;
  u16 o[16];
#pragma unroll
  for (int e = 0; e < 16; ++e) o[e] = f2bf(tl[n][cc * 16 + e]);
  u16* dp = dst + (size_t)(tn * 64 + n) * K + tk * 64 + cc * 16;
  *(uint4*)(dp) = *(uint4*)&o[0];
  *(uint4*)(dp + 8) = *(uint4*)&o[8];
}

__global__ __launch_bounds__(256) void wconv_layer(
    const float* __restrict__ Wq, const float* __restrict__ Wk, const float* __restrict__ Wv,
    const float* __restrict__ Wo, const float* __restrict__ W1, const float* __restrict__ W2,
    u16* __restrict__ Wqkvt, u16* __restrict__ Wot, u16* __restrict__ W1t, u16* __restrict__ W2t) {
  int b = blockIdx.x;
  if (b < 64) { wtconv_tile(Wq, Wqkvt, 512, 512, b >> 3, b & 7); return; }
  if (b < 128) { b -= 64; wtconv_tile(Wk, Wqkvt + 512 * 512, 512, 512, b >> 3, b & 7); return; }
  if (b < 192) { b -= 128; wtconv_tile(Wv, Wqkvt + 1024 * 512, 512, 512, b >> 3, b & 7); return; }
  if (b < 256) { b -= 192; wtconv_tile(Wo, Wot, 512, 512, b >> 3, b & 7); return; }
  if (b < 512) { b -= 256; wtconv_tile(W1, W1t, 512, FFD, b >> 3, b & 7); return; }
  b -= 512; wtconv_tile(W2, W2t, FFD, 512, b >> 5, b & 31);
}

// ---------------- bf16 MFMA GEMM: C = A[M,K]bf16 @ Bt[N,K]bf16^T + bias ----------------
__global__ __launch_bounds__(256) void gemm_bf16(
    const u16* __restrict__ A, const u16* __restrict__ Bt, const float* __restrict__ bias,
    float* __restrict__ Cf, u16* __restrict__ Cb,
    int M, int N, int K, int act, int scaleLT) {
  __shared__ u16 As[64 * 64];
  __shared__ u16 Bs[128 * 64];
  const int tid = threadIdx.x, w = tid >> 6, lane = tid & 63;
  const int lr = lane & 15, lg = lane >> 4;
  const int row0 = blockIdx.y * 64, col0 = blockIdx.x * 128;
  const int srow = lane >> 3;
  const int aoff = ((lane & 7) ^ srow) * 8;
  const f32x4 z4 = {0.f, 0.f, 0.f, 0.f};
  f32x4 acc[4][2];
#pragma unroll
  for (int mi = 0; mi < 4; ++mi)
#pragma unroll
    for (int ni = 0; ni < 2; ++ni) acc[mi][ni] = z4;

  const int nw = w * 32;
  for (int k0 = 0; k0 < K; k0 += 64) {
#pragma unroll
    for (int i = 0; i < 2; ++i)
      gload_lds16(A + (size_t)(row0 + w * 16 + i * 8 + srow) * K + k0 + aoff,
                  As + (w * 16 + i * 8) * 64);
#pragma unroll
    for (int i = 0; i < 4; ++i)
      gload_lds16(Bt + (size_t)(col0 + w * 32 + i * 8 + srow) * K + k0 + aoff,
                  Bs + (w * 32 + i * 8) * 64);
    __syncthreads();
#pragma unroll
    for (int kh = 0; kh < 2; ++kh) {
      bf16x8 a[4], b[2];
#pragma unroll
      for (int mi = 0; mi < 4; ++mi) {
        int r = mi * 16 + lr;
        a[mi] = *(const bf16x8*)(As + r * 64 + (((kh * 4 + lg) ^ (r & 7)) << 3));
      }
#pragma unroll
      for (int ni = 0; ni < 2; ++ni) {
        int r = nw + ni * 16 + lr;
        b[ni] = *(const bf16x8*)(Bs + r * 64 + (((kh * 4 + lg) ^ (r & 7)) << 3));
      }
#pragma unroll
      for (int mi = 0; mi < 4; ++mi)
#pragma unroll
        for (int ni = 0; ni < 2; ++ni)
          acc[mi][ni] = __builtin_amdgcn_mfma_f32_16x16x32_bf16(a[mi], b[ni], acc[mi][ni], 0, 0, 0);
    }
    __syncthreads();
  }
#pragma unroll
  for (int mi = 0; mi < 4; ++mi) {
    int r = row0 + mi * 16 + lg * 4;
#pragma unroll
    for (int ni = 0; ni < 2; ++ni) {
      int c = col0 + nw + ni * 16 + lr;
      float bs = bias[c];
      float sc = (c < scaleLT) ? SCALEF : 1.0f;
#pragma unroll
      for (int j = 0; j < 4; ++j) {
        float v = acc[mi][ni][j] + bs;
        if (act == 1) v = 0.5f * v * (1.0f + erff(v * 0.70710678118654752f));
        size_t idx = (size_t)(r + j) * N + c;
        if (Cf) Cf[idx] = v;
        if (Cb) Cb[idx] = f2bf(v * sc);
      }
    }
  }
}

// ---------------- rel projection from packed bf16 qkv ----------------
__global__ void proj_relbf_kernel(const u16* __restrict__ x, const float* __restrict__ Kr,
                                  const float* __restrict__ ekrs, float scale_mul,
                                  float* __restrict__ outp) {
  int idx = blockIdx.x * 256 + threadIdx.x;
  if (idx >= BB * HH * LL * NDB) return;
  int d = idx % NDB;
  int rest = idx / NDB;
  int l = rest & (LL - 1);
  int bh = rest >> 9;
  int h = bh & (HH - 1);
  int b = bh >> 4;
  const u16* xr = x + ((size_t)(b * LL + l)) * QKS + h * KHD;
  const float* kr = Kr + d * KHD;
  float s = 0.f;
#pragma unroll
  for (int kk = 0; kk < KHD; ++kk) s += bf2f(xr[kk]) * kr[kk];
  s *= scale_mul;
  if (ekrs) s += SCALEF * ekrs[d];
  outp[idx] = s;
}

// ---------------- Sb[b,h,l,x] = u32: f32 bias with d packed in low 4 mantissa bits ----------------
__global__ __launch_bounds__(256) void sbias_kernel(
    const unsigned char* __restrict__ didx8, const float* __restrict__ qE2,
    const float* __restrict__ kE2, u32* __restrict__ Sb) {
  const int l = blockIdx.x, b = blockIdx.y, tid = threadIdx.x;
  __shared__ unsigned char dloc[512];
  __shared__ float qes[HH][NDB];
  if (tid < 128) ((u32*)dloc)[tid] = ((const u32*)(didx8 + ((size_t)(b * LL + l)) * LL))[tid];
  if (tid < HH * NDB) {
    int hh = tid / NDB, dd = tid % NDB;
    qes[hh][dd] = qE2[(((size_t)(b * HH + hh)) * LL + l) * NDB + dd];
  }
  __syncthreads();
#pragma unroll
  for (int it = 0; it < 32; ++it) {
    int idx = it * 256 + tid;
    int hh = idx >> 9, x = idx & 511;
    int d = dloc[x];
    float kv = kE2[(((size_t)(b * HH + hh)) * LL + x) * NDB + d];
    float f = qes[hh][d] + kv;
    u32 u = (__builtin_bit_cast(u32, f) & ~15u) | (u32)d;
    Sb[(((size_t)(b * HH + hh)) * LL + l) * LL + x] = u;
  }
}

// ---------------- v (packed bf16 cols 1024..1535) -> vt [b,h,kh,x] bf16 ----------------
__global__ __launch_bounds__(256) void vtrans_kernel(const u16* __restrict__ qkv, u16* __restrict__ vt) {
  const int h = blockIdx.x, b = blockIdx.y, tid = threadIdx.x;
  __shared__ u16 tile[KHD][520];
  for (int it = 0; it < 64; ++it) {
    int idx = it * 256 + tid;
    int x = idx >> 5, kh = idx & 31;
    tile[kh][x] = qkv[((size_t)(b * LL) + x) * QKS + 1024 + h * KHD + kh];
  }
  __syncthreads();
  int r = tid >> 3, seg = tid & 7;
  uint4* dst = (uint4*)(vt + ((size_t)(b * HH + h) * KHD + r) * LL);
  const uint4* src = (const uint4*)(&tile[r][0]);
#pragma unroll
  for (int j = 0; j < 8; ++j) dst[seg + j * 8] = src[seg + j * 8];
}

// ---------------- attention v3: block = (16 q-rows, h, b); 4 waves kv-split 128 keys each ----------------
// Bias+d come from packed Sb (one coalesced u32 load per pair, bias -> MFMA C-in).
// No bulk LDS staging: K/V/Sb read from global (L2/L3 resident). LDS ~11 KB -> ~5 blocks/CU.
// No-max softmax (scores LN-bounded, fp32 exp exact): partial (o, rsum, hist) merged via LDS atomics.
__global__ __launch_bounds__(256, 5) void attn3_kernel(
    const u16* __restrict__ qkv, const u16* __restrict__ vtbf, const u32* __restrict__ Sb,
    const float* __restrict__ Vsum, u16* __restrict__ z) {
  const int qr = blockIdx.x, h = blockIdx.y, b = blockIdx.z;
  const int tid = threadIdx.x, lane = tid & 63, w = tid >> 6;
  const int lr = lane & 15, lg = lane >> 4;
  const int row0 = qr * 16;

  __shared__ float osh[16][34];     // 2176 B, padded
  __shared__ float rs_sh[16];
  __shared__ float hist[16][15];    // 960 B, padded
  __shared__ u16 Pt[4][16][40];     // 5120 B, per-wave
  __shared__ float Vsums[NDB][KHD]; // 1792 B

  if (tid < 136) ((float4*)osh)[tid] = float4{0.f, 0.f, 0.f, 0.f};
  if (tid < 16) rs_sh[tid] = 0.f;
  if (tid < 60) ((float4*)hist)[tid] = float4{0.f, 0.f, 0.f, 0.f};
  if (tid < 112) ((float4*)Vsums)[tid] = ((const float4*)Vsum)[tid];

  const bf16x8 aQ = *(const bf16x8*)(qkv + ((size_t)(b * LL + row0 + lr)) * QKS + h * KHD + lg * 8);

  __syncthreads();

  f32x4 o0 = {0.f, 0.f, 0.f, 0.f}, o1 = {0.f, 0.f, 0.f, 0.f};
  float rsum[4] = {0.f, 0.f, 0.f, 0.f};

  const u16* kbase = qkv + (size_t)b * LL * QKS + 512 + h * KHD + lg * 8;
  const u16* vbase = vtbf + ((size_t)(b * HH + h) * KHD) * LL;
  const u32* sbase = Sb + (((size_t)(b * HH + h)) * LL + row0) * LL;

  for (int ct = 0; ct < 4; ++ct) {
    const int x0 = w * 128 + ct * 32;
    bf16x8 bk0 = *(const bf16x8*)(kbase + (size_t)(x0 + lr) * QKS);
    bf16x8 bk1 = *(const bf16x8*)(kbase + (size_t)(x0 + 16 + lr) * QKS);
    u32 sb0[4], sb1[4];
    f32x4 c0, c1;
#pragma unroll
    for (int i = 0; i < 4; ++i) {
      const int rl = lg * 4 + i;
      sb0[i] = sbase[(size_t)rl * LL + x0 + lr];
      sb1[i] = sbase[(size_t)rl * LL + x0 + 16 + lr];
      c0[i] = __builtin_bit_cast(float, sb0[i]);
      c1[i] = __builtin_bit_cast(float, sb1[i]);
    }
    f32x4 s0 = __builtin_amdgcn_mfma_f32_16x16x32_bf16(aQ, bk0, c0, 0, 0, 0);
    f32x4 s1 = __builtin_amdgcn_mfma_f32_16x16x32_bf16(aQ, bk1, c1, 0, 0, 0);

#pragma unroll
    for (int i = 0; i < 4; ++i) {
      const int rl = lg * 4 + i;
      float p0 = __expf(s0[i]);
      float p1 = __expf(s1[i]);
      rsum[i] += p0 + p1;
      atomicAdd(&hist[rl][sb0[i] & 15u], p0);
      atomicAdd(&hist[rl][sb1[i] & 15u], p1);
      Pt[w][rl][lr] = f2bf(p0);
      Pt[w][rl][16 + lr] = f2bf(p1);
    }
    // per-wave LDS ordering: Pt writes drain before this read (compiler lgkmcnt)
    bf16x8 aP = *(const bf16x8*)(&Pt[w][lr][lg * 8]);
    bf16x8 vb0 = *(const bf16x8*)(vbase + (size_t)lr * LL + x0 + lg * 8);
    bf16x8 vb1 = *(const bf16x8*)(vbase + (size_t)(16 + lr) * LL + x0 + lg * 8);
    o0 = __builtin_amdgcn_mfma_f32_16x16x32_bf16(aP, vb0, o0, 0, 0, 0);
    o1 = __builtin_amdgcn_mfma_f32_16x16x32_bf16(aP, vb1, o1, 0, 0, 0);
  }

  // merge partials across the 4 kv-split waves
#pragma unroll
  for (int i = 0; i < 4; ++i) {
    const int rl = lg * 4 + i;
    float s = rsum[i];
    s += __shfl_xor(s, 1);
    s += __shfl_xor(s, 2);
    s += __shfl_xor(s, 4);
    s += __shfl_xor(s, 8);
    if (lr == 0) atomicAdd(&rs_sh[rl], s);
    atomicAdd(&osh[rl][lr], o0[i]);
    atomicAdd(&osh[rl][16 + lr], o1[i]);
  }
  __syncthreads();

  // epilogue: 256 threads cover 16 rows x 32 cols (2 cols each)
  const int r = tid >> 4, c = tid & 15;
  const float inv = 1.0f / rs_sh[r];
  float vb_0 = 0.f, vb_1 = 0.f;
#pragma unroll
  for (int d = 0; d < NDB; ++d) {
    float a = hist[r][d];
    vb_0 += a * Vsums[d][c];
    vb_1 += a * Vsums[d][16 + c];
  }
  const size_t orow = ((size_t)(b * LL + row0 + r)) * DDIM + h * KHD;
  z[orow + c] = f2bf((osh[r][c] + vb_0) * inv);
  z[orow + 16 + c] = f2bf((osh[r][16 + c] + vb_1) * inv);
}

// ---------------- out = LN(X + Y), f32 + bf16 ----------------
__global__ __launch_bounds__(256) void add_ln_kernel(
    const float* __restrict__ X, const float* __restrict__ Y,
    const float* __restrict__ g, const float* __restrict__ be,
    float* __restrict__ out, u16* __restrict__ outb) {
  const int row = blockIdx.x, tid = threadIdx.x;
  const int lane = tid & 63, wid = tid >> 6;
  __shared__ float red[4];
  const size_t base = (size_t)row * DDIM;
  float x0 = X[base + tid] + Y[base + tid];
  float x1 = X[base + tid + 256] + Y[base + tid + 256];
  float s = wredSum(x0 + x1);
  if (lane == 0) red[wid] = s;
  __syncthreads();
  float mu = (red[0] + red[1] + red[2] + red[3]) * (1.0f / DDIM);
  __syncthreads();
  float d0 = x0 - mu, d1 = x1 - mu;
  float vs = wredSum(d0 * d0 + d1 * d1);
  if (lane == 0) red[wid] = vs;
  __syncthreads();
  float var = (red[0] + red[1] + red[2] + red[3]) * (1.0f / DDIM);
  float inv = rsqrtf(var + 1e-5f);
  float r0 = d0 * inv * g[tid] + be[tid];
  float r1 = d1 * inv * g[tid + 256] + be[tid + 256];
  out[base + tid] = r0;
  out[base + tid + 256] = r1;
  outb[base + tid] = f2bf(r0);
  outb[base + tid + 256] = f2bf(r1);
}

// ---------------- pooled[b,d] = sum_l h[b,l,d] ----------------
__global__ void pool_kernel(const float* __restrict__ h, float* __restrict__ pooled, int n) {
  int i = blockIdx.x * 256 + threadIdx.x;
  if (i >= n) return;
  int b = i >> 9, d = i & 511;
  float s = 0.f;
  for (int l = 0; l < LL; ++l) s += h[(size_t)(b * LL + l) * DDIM + d];
  pooled[i] = s;
}

// ---------------- head ----------------
__global__ __launch_bounds__(256) void head_kernel(
    const float* __restrict__ pooled, const float* __restrict__ Wm1,
    const float* __restrict__ bm1, const float* __restrict__ Wm2,
    const float* __restrict__ bm2, float* __restrict__ out) {
  int b = blockIdx.x, tid = threadIdx.x;
  const float* p = pooled + b * DDIM;
  float part = 0.f;
  for (int jj = 0; jj < 2; ++jj) {
    int j = tid + jj * 256;
    float s = bm1[j];
    for (int dd = 0; dd < DDIM; ++dd) s += p[dd] * Wm1[(size_t)dd * MMD + j];
    part += fmaxf(s, 0.f) * Wm2[j];
  }
  __shared__ float red[4];
  int lane = tid & 63, wid = tid >> 6;
  float ssum = wredSum(part);
  if (lane == 0) red[wid] = ssum;
  __syncthreads();
  if (tid == 0) out[b] = red[0] + red[1] + red[2] + red[3] + bm2[0];
}

extern "C" void kernel_launch(void* const* d_in, const int* in_sizes, int n_in,
                              void* d_out, int out_size, void* d_ws, size_t ws_size,
                              hipStream_t stream) {
  const int* cell_types = (const int*)d_in[0];
  const float* distances = (const float*)d_in[1];
  const float* cell_emb = (const float*)d_in[2];
  const float* Kqk = (const float*)d_in[3];
  const float* Kqr = (const float*)d_in[4];
  const float* Kkr = (const float*)d_in[5];
  const float* Vqk = (const float*)d_in[6];
  const float* Vqr = (const float*)d_in[7];
  const float* Vkr = (const float*)d_in[8];
  const float* Wq = (const float*)d_in[9];
  const float* Wk = (const float*)d_in[10];
  const float* Wv = (const float*)d_in[11];
  const float* Wo = (const float*)d_in[12];
  const float* bq = (const float*)d_in[13];
  const float* bk = (const float*)d_in[14];
  const float* bv = (const float*)d_in[15];
  const float* bo = (const float*)d_in[16];
  const float* W1 = (const float*)d_in[17];
  const float* b1 = (const float*)d_in[18];
  const float* W2 = (const float*)d_in[19];
  const float* b2 = (const float*)d_in[20];
  const float* g1 = (const float*)d_in[21];
  const float* be1 = (const float*)d_in[22];
  const float* g2 = (const float*)d_in[23];
  const float* be2 = (const float*)d_in[24];
  const float* Wm1 = (const float*)d_in[25];
  const float* bm1 = (const float*)d_in[26];
  const float* Wm2 = (const float*)d_in[27];
  const float* bm2 = (const float*)d_in[28];

  char* w = (char*)d_ws;
  auto alloc = [&](size_t bytes) { void* p = (void*)w; w += (bytes + 255) & ~(size_t)255; return p; };
  unsigned char* didx8 = (unsigned char*)alloc(sizeof(unsigned char) * BB * LL * LL);
  float* h    = (float*)alloc(sizeof(float) * BB * LL * DDIM);
  u16* hbf    = (u16*)alloc(sizeof(u16) * BB * LL * DDIM);
  float* h2   = (float*)alloc(sizeof(float) * BB * LL * DDIM);
  u16* h2bf   = (u16*)alloc(sizeof(u16) * BB * LL * DDIM);
  u16* qkvbf  = (u16*)alloc(sizeof(u16) * BB * LL * QKS);
  float* ob   = (float*)alloc(sizeof(float) * BB * LL * DDIM);
  u16* f1bf   = (u16*)alloc(sizeof(u16) * BB * LL * FFD);
  u16* zbf    = (u16*)alloc(sizeof(u16) * BB * LL * DDIM);
  u16* vtbf   = (u16*)alloc(sizeof(u16) * BB * HH * KHD * LL);
  float* qE2  = (float*)alloc(sizeof(float) * BB * HH * LL * NDB);
  float* kE2  = (float*)alloc(sizeof(float) * BB * HH * LL * NDB);
  u32* Sb     = (u32*)alloc(sizeof(u32) * (size_t)BB * HH * LL * LL);
  u16* Wqkvt  = (u16*)alloc(sizeof(u16) * QKS * DDIM);
  u16* Wot    = (u16*)alloc(sizeof(u16) * DDIM * DDIM);
  u16* W1t    = (u16*)alloc(sizeof(u16) * FFD * DDIM);
  u16* W2t    = (u16*)alloc(sizeof(u16) * DDIM * FFD);
  float* bqkv = (float*)alloc(sizeof(float) * NLAY * QKS);
  float* Vsum = (float*)alloc(sizeof(float) * NDB * KHD);
  float* EkrS = (float*)alloc(sizeof(float) * NDB);
  float* pooled = (float*)alloc(sizeof(float) * BB * DDIM);

  const int Mrows = BB * LL;

  bucketize_kernel<<<(BB * LL * LL + 255) / 256, 256, 0, stream>>>(distances, didx8, BB * LL * LL);
  embed_kernel<<<(BB * LL * DDIM + 255) / 256, 256, 0, stream>>>(cell_types, cell_emb, h, hbf, BB * LL * DDIM);
  prep_kernel<<<1, 512, 0, stream>>>(Vqk, Vqr, Vkr, Kkr, Vsum, EkrS);
  biaspack_kernel<<<(NLAY * QKS + 255) / 256, 256, 0, stream>>>(bq, bk, bv, bqkv);

  const int nrel = BB * HH * LL * NDB;

  for (int lay = 0; lay < NLAY; ++lay) {
    wconv_layer<<<768, 256, 0, stream>>>(
        Wq + (size_t)lay * DDIM * DDIM, Wk + (size_t)lay * DDIM * DDIM,
        Wv + (size_t)lay * DDIM * DDIM, Wo + (size_t)lay * DDIM * DDIM,
        W1 + (size_t)lay * DDIM * FFD, W2 + (size_t)lay * FFD * DDIM,
        Wqkvt, Wot, W1t, W2t);

    gemm_bf16<<<dim3(QKS / 128, Mrows / 64), 256, 0, stream>>>(
        hbf, Wqkvt, bqkv + (size_t)lay * QKS, nullptr, qkvbf, Mrows, QKS, DDIM, 0, 512);

    proj_relbf_kernel<<<(nrel + 255) / 256, 256, 0, stream>>>(qkvbf, Kqk, nullptr, 1.0f, qE2);
    proj_relbf_kernel<<<(nrel + 255) / 256, 256, 0, stream>>>(qkvbf + 512, Kqr, EkrS, SCALEF, kE2);
    sbias_kernel<<<dim3(LL, BB), 256, 0, stream>>>(didx8, qE2, kE2, Sb);
    vtrans_kernel<<<dim3(HH, BB), 256, 0, stream>>>(qkvbf, vtbf);
    attn3_kernel<<<dim3(32, HH, BB), 256, 0, stream>>>(qkvbf, vtbf, Sb, Vsum, zbf);

    gemm_bf16<<<dim3(DDIM / 128, Mrows / 64), 256, 0, stream>>>(
        zbf, Wot, bo + (size_t)lay * DDIM, ob, nullptr, Mrows, DDIM, DDIM, 0, 0);
    add_ln_kernel<<<Mrows, 256, 0, stream>>>(h, ob, g1 + (size_t)lay * DDIM, be1 + (size_t)lay * DDIM, h2, h2bf);
    gemm_bf16<<<dim3(FFD / 128, Mrows / 64), 256, 0, stream>>>(
        h2bf, W1t, b1 + (size_t)lay * FFD, nullptr, f1bf, Mrows, FFD, DDIM, 1, 0);
    gemm_bf16<<<dim3(DDIM / 128, Mrows / 64), 256, 0, stream>>>(
        f1bf, W2t, b2 + (size_t)lay * DDIM, ob, nullptr, Mrows, DDIM, FFD, 0, 0);
    add_ln_kernel<<<Mrows, 256, 0, stream>>>(h2, ob, g2 + (size_t)lay * DDIM, be2 + (size_t)lay * DDIM, h, hbf);
  }

  pool_kernel<<<(BB * DDIM + 255) / 256, 256, 0, stream>>>(h, pooled, BB * DDIM);
  head_kernel<<<BB, 256, 0, stream>>>(pooled, Wm1, bm1, Wm2, bm2, (float*)d_out);
}

// Round 6
// 1846.948 us; speedup vs baseline: 1.1331x; 1.1331x over previous
//
#include <hip/hip_runtime.h>
#include <math.h>

#define NLAY 8
#define BB 4
#define LL 512
#define DDIM 512
#define HH 16
#define KHD 32
#define FFD 2048
#define MMD 512
#define NDB 14
#define QKS 1536
#define SCALEF 0.17677669529663687f

typedef unsigned short u16;
typedef unsigned int u32;
typedef __attribute__((ext_vector_type(8))) short bf16x8;
typedef __attribute__((ext_vector_type(4))) float f32x4;

__device__ __forceinline__ u16 f2bf(float f) {
  unsigned u = __builtin_bit_cast(unsigned, f);
  u = (u + 0x7fffu + ((u >> 16) & 1u)) >> 16;
  return (u16)u;
}
__device__ __forceinline__ float bf2f(u16 v) {
  unsigned u = ((unsigned)v) << 16;
  return __builtin_bit_cast(float, u);
}
__device__ __forceinline__ float wredSum(float v) {
#pragma unroll
  for (int o = 32; o > 0; o >>= 1) v += __shfl_down(v, o);
  return v;
}
__device__ __forceinline__ void gload_lds16(const u16* g, u16* l) {
  __builtin_amdgcn_global_load_lds((const __attribute__((address_space(1))) void*)g,
                                   (__attribute__((address_space(3))) void*)l, 16, 0, 0);
}

// ---------------- bucketize -> uint8 ----------------
__global__ void bucketize_kernel(const float* __restrict__ dist, unsigned char* __restrict__ didx, int n) {
  int i = blockIdx.x * 256 + threadIdx.x;
  if (i >= n) return;
  float d = dist[i];
  int c = 0;
#pragma unroll
  for (int t = 1; t <= NDB; ++t) c += (10.0f * (float)t < d) ? 1 : 0;
  didx[i] = (unsigned char)(c > (NDB - 1) ? (NDB - 1) : c);
}

// ---------------- h = cell_emb[cell_types] (f32 + bf16) ----------------
__global__ void embed_kernel(const int* __restrict__ ct, const float* __restrict__ emb,
                             float* __restrict__ h, u16* __restrict__ hbf, int n) {
  int i = blockIdx.x * 256 + threadIdx.x;
  if (i >= n) return;
  int bl = i >> 9, d = i & 511;
  float v = emb[ct[bl] * DDIM + d];
  h[i] = v;
  hbf[i] = f2bf(v);
}

// ---------------- Vsum, EkrS ----------------
__global__ void prep_kernel(const float* __restrict__ Vqk, const float* __restrict__ Vqr,
                            const float* __restrict__ Vkr, const float* __restrict__ Kkr,
                            float* __restrict__ Vsum, float* __restrict__ EkrS) {
  int tid = threadIdx.x;
  if (tid < NDB * KHD) Vsum[tid] = Vqk[tid] + Vqr[tid] + Vkr[tid];
  if (tid < NDB) {
    float s = 0.f;
    for (int kk = 0; kk < KHD; ++kk) s += Kkr[tid * KHD + kk];
    EkrS[tid] = s;
  }
}

// ---------------- packed qkv bias [NLAY][1536] ----------------
__global__ void biaspack_kernel(const float* __restrict__ bq, const float* __restrict__ bk,
                                const float* __restrict__ bv, float* __restrict__ bqkv) {
  int i = blockIdx.x * 256 + threadIdx.x;
  if (i >= NLAY * QKS) return;
  int lay = i / QKS, c = i % QKS;
  float v;
  if (c < 512) v = bq[lay * DDIM + c];
  else if (c < 1024) v = bk[lay * DDIM + c - 512];
  else v = bv[lay * DDIM + c - 1024];
  bqkv[i] = v;
}

// ---------------- per-layer weight transpose+convert: src f32 [K,N] -> dst bf16 [N,K] ----------------
__device__ __forceinline__ void wtconv_tile(const float* __restrict__ src, u16* __restrict__ dst,
                                            int K, int N, int tn, int tk) {
  __shared__ float tl[64][65];
  const int t = threadIdx.x;
#pragma unroll
  for (int p = 0; p < 4; ++p) {
    int k = tk * 64 + p * 16 + (t >> 4);
    int n = tn * 64 + (t & 15) * 4;
    float4 v = *(const float4*)(src + (size_t)k * N + n);
    tl[(t & 15) * 4 + 0][p * 16 + (t >> 4)] = v.x;
    tl[(t & 15) * 4 + 1][p * 16 + (t >> 4)] = v.y;
    tl[(t & 15) * 4 + 2][p * 16 + (t >> 4)] = v.z;
    tl[(t & 15) * 4 + 3][p * 16 + (t >> 4)] = v.w;
  }
  __syncthreads();
  int n = t >> 2, cc = t & 3;
  u16 o[16];
#pragma unroll
  for (int e = 0; e < 16; ++e) o[e] = f2bf(tl[n][cc * 16 + e]);
  u16* dp = dst + (size_t)(tn * 64 + n) * K + tk * 64 + cc * 16;
  *(uint4*)(dp) = *(uint4*)&o[0];
  *(uint4*)(dp + 8) = *(uint4*)&o[8];
}

__global__ __launch_bounds__(256) void wconv_layer(
    const float* __restrict__ Wq, const float* __restrict__ Wk, const float* __restrict__ Wv,
    const float* __restrict__ Wo, const float* __restrict__ W1, const float* __restrict__ W2,
    u16* __restrict__ Wqkvt, u16* __restrict__ Wot, u16* __restrict__ W1t, u16* __restrict__ W2t) {
  int b = blockIdx.x;
  if (b < 64) { wtconv_tile(Wq, Wqkvt, 512, 512, b >> 3, b & 7); return; }
  if (b < 128) { b -= 64; wtconv_tile(Wk, Wqkvt + 512 * 512, 512, 512, b >> 3, b & 7); return; }
  if (b < 192) { b -= 128; wtconv_tile(Wv, Wqkvt + 1024 * 512, 512, 512, b >> 3, b & 7); return; }
  if (b < 256) { b -= 192; wtconv_tile(Wo, Wot, 512, 512, b >> 3, b & 7); return; }
  if (b < 512) { b -= 256; wtconv_tile(W1, W1t, 512, FFD, b >> 3, b & 7); return; }
  b -= 512; wtconv_tile(W2, W2t, FFD, 512, b >> 5, b & 31);
}

// ---------------- bf16 MFMA GEMM: C = A[M,K]bf16 @ Bt[N,K]bf16^T + bias ----------------
__global__ __launch_bounds__(256) void gemm_bf16(
    const u16* __restrict__ A, const u16* __restrict__ Bt, const float* __restrict__ bias,
    float* __restrict__ Cf, u16* __restrict__ Cb,
    int M, int N, int K, int act, int scaleLT) {
  __shared__ u16 As[64 * 64];
  __shared__ u16 Bs[128 * 64];
  const int tid = threadIdx.x, w = tid >> 6, lane = tid & 63;
  const int lr = lane & 15, lg = lane >> 4;
  const int row0 = blockIdx.y * 64, col0 = blockIdx.x * 128;
  const int srow = lane >> 3;
  const int aoff = ((lane & 7) ^ srow) * 8;
  const f32x4 z4 = {0.f, 0.f, 0.f, 0.f};
  f32x4 acc[4][2];
#pragma unroll
  for (int mi = 0; mi < 4; ++mi)
#pragma unroll
    for (int ni = 0; ni < 2; ++ni) acc[mi][ni] = z4;

  const int nw = w * 32;
  for (int k0 = 0; k0 < K; k0 += 64) {
#pragma unroll
    for (int i = 0; i < 2; ++i)
      gload_lds16(A + (size_t)(row0 + w * 16 + i * 8 + srow) * K + k0 + aoff,
                  As + (w * 16 + i * 8) * 64);
#pragma unroll
    for (int i = 0; i < 4; ++i)
      gload_lds16(Bt + (size_t)(col0 + w * 32 + i * 8 + srow) * K + k0 + aoff,
                  Bs + (w * 32 + i * 8) * 64);
    __syncthreads();
#pragma unroll
    for (int kh = 0; kh < 2; ++kh) {
      bf16x8 a[4], b[2];
#pragma unroll
      for (int mi = 0; mi < 4; ++mi) {
        int r = mi * 16 + lr;
        a[mi] = *(const bf16x8*)(As + r * 64 + (((kh * 4 + lg) ^ (r & 7)) << 3));
      }
#pragma unroll
      for (int ni = 0; ni < 2; ++ni) {
        int r = nw + ni * 16 + lr;
        b[ni] = *(const bf16x8*)(Bs + r * 64 + (((kh * 4 + lg) ^ (r & 7)) << 3));
      }
#pragma unroll
      for (int mi = 0; mi < 4; ++mi)
#pragma unroll
        for (int ni = 0; ni < 2; ++ni)
          acc[mi][ni] = __builtin_amdgcn_mfma_f32_16x16x32_bf16(a[mi], b[ni], acc[mi][ni], 0, 0, 0);
    }
    __syncthreads();
  }
#pragma unroll
  for (int mi = 0; mi < 4; ++mi) {
    int r = row0 + mi * 16 + lg * 4;
#pragma unroll
    for (int ni = 0; ni < 2; ++ni) {
      int c = col0 + nw + ni * 16 + lr;
      float bs = bias[c];
      float sc = (c < scaleLT) ? SCALEF : 1.0f;
#pragma unroll
      for (int j = 0; j < 4; ++j) {
        float v = acc[mi][ni][j] + bs;
        if (act == 1) v = 0.5f * v * (1.0f + erff(v * 0.70710678118654752f));
        size_t idx = (size_t)(r + j) * N + c;
        if (Cf) Cf[idx] = v;
        if (Cb) Cb[idx] = f2bf(v * sc);
      }
    }
  }
}

// ---------------- rel projection (f32 out, for qE) ----------------
__global__ void proj_relbf_kernel(const u16* __restrict__ x, const float* __restrict__ Kr,
                                  const float* __restrict__ ekrs, float scale_mul,
                                  float* __restrict__ outp) {
  int idx = blockIdx.x * 256 + threadIdx.x;
  if (idx >= BB * HH * LL * NDB) return;
  int d = idx % NDB;
  int rest = idx / NDB;
  int l = rest & (LL - 1);
  int bh = rest >> 9;
  int h = bh & (HH - 1);
  int b = bh >> 4;
  const u16* xr = x + ((size_t)(b * LL + l)) * QKS + h * KHD;
  const float* kr = Kr + d * KHD;
  float s = 0.f;
#pragma unroll
  for (int kk = 0; kk < KHD; ++kk) s += bf2f(xr[kk]) * kr[kk];
  s *= scale_mul;
  if (ekrs) s += SCALEF * ekrs[d];
  outp[idx] = s;
}

// ---------------- rel projection (bf16 out, [bhx][16] padded layout, for kE) ----------------
__global__ void proj_relbf16_kernel(const u16* __restrict__ x, const float* __restrict__ Kr,
                                    const float* __restrict__ ekrs, float scale_mul,
                                    u16* __restrict__ outp) {
  int idx = blockIdx.x * 256 + threadIdx.x;
  if (idx >= BB * HH * LL * NDB) return;
  int d = idx % NDB;
  int rest = idx / NDB;
  int l = rest & (LL - 1);
  int bh = rest >> 9;
  int h = bh & (HH - 1);
  int b = bh >> 4;
  const u16* xr = x + ((size_t)(b * LL + l)) * QKS + h * KHD;
  const float* kr = Kr + d * KHD;
  float s = 0.f;
#pragma unroll
  for (int kk = 0; kk < KHD; ++kk) s += bf2f(xr[kk]) * kr[kk];
  s *= scale_mul;
  if (ekrs) s += SCALEF * ekrs[d];
  outp[(size_t)rest * 16 + d] = f2bf(s);
}

// ---------------- v (packed bf16 cols 1024..1535) -> vt [b,h,kh,x] bf16 ----------------
__global__ __launch_bounds__(256) void vtrans_kernel(const u16* __restrict__ qkv, u16* __restrict__ vt) {
  const int h = blockIdx.x, b = blockIdx.y, tid = threadIdx.x;
  __shared__ u16 tile[KHD][520];
  for (int it = 0; it < 64; ++it) {
    int idx = it * 256 + tid;
    int x = idx >> 5, kh = idx & 31;
    tile[kh][x] = qkv[((size_t)(b * LL) + x) * QKS + 1024 + h * KHD + kh];
  }
  __syncthreads();
  int r = tid >> 3, seg = tid & 7;
  uint4* dst = (uint4*)(vt + ((size_t)(b * HH + h) * KHD + r) * LL);
  const uint4* src = (const uint4*)(&tile[r][0]);
#pragma unroll
  for (int j = 0; j < 8; ++j) dst[seg + j * 8] = src[seg + j * 8];
}

// ---------------- attention v4: block = (16 q-rows, h, b); 4 waves kv-split 128 keys each ----------------
// Bias gathered in-kernel from cache-resident sources (didx L2, kEbf L1 16KB/head, qE in LDS).
// Per-wave hist (no contention, no in-loop barriers); rsum derived from hist; no-max softmax.
// LDS ~14KB, ~48 VGPR -> all 8 blocks/CU resident.
__global__ __launch_bounds__(256, 4) void attn4_kernel(
    const u16* __restrict__ qkv, const u16* __restrict__ vtbf,
    const float* __restrict__ qE2, const u16* __restrict__ kEbf,
    const unsigned char* __restrict__ didx8,
    const float* __restrict__ Vsum, u16* __restrict__ z) {
  const int qr = blockIdx.x, h = blockIdx.y, b = blockIdx.z;
  const int tid = threadIdx.x, lane = tid & 63, w = tid >> 6;
  const int lr = lane & 15, lg = lane >> 4;
  const int row0 = qr * 16;

  __shared__ float qEs[16][14];      // 896 B
  __shared__ float hist[4][16][16];  // 4 KB, per-wave
  __shared__ u16 Pt[4][16][40];      // 5 KB, per-wave
  __shared__ float Vsums[NDB][KHD];  // 1.8 KB
  __shared__ float osh[16][33];      // 2.1 KB

  if (tid < 56) ((float4*)&qEs[0][0])[tid] =
      ((const float4*)(qE2 + (((size_t)(b * HH + h)) * LL + row0) * NDB))[tid];
  if (tid < 112) ((float4*)Vsums)[tid] = ((const float4*)Vsum)[tid];
  if (tid < 132) ((float4*)&osh[0][0])[tid] = float4{0.f, 0.f, 0.f, 0.f};
  ((float4*)hist)[tid] = float4{0.f, 0.f, 0.f, 0.f};  // 256 float4 == whole array

  const bf16x8 aQ = *(const bf16x8*)(qkv + ((size_t)(b * LL + row0 + lr)) * QKS + h * KHD + lg * 8);

  __syncthreads();  // staging + init complete (only block-wide barrier before epilogue)

  f32x4 o0 = {0.f, 0.f, 0.f, 0.f}, o1 = {0.f, 0.f, 0.f, 0.f};
  const f32x4 zero4 = {0.f, 0.f, 0.f, 0.f};

  const u16* kbase = qkv + (size_t)b * LL * QKS + 512 + h * KHD + lg * 8;
  const u16* vbase = vtbf + ((size_t)(b * HH + h) * KHD) * LL;
  const u16* kebase = kEbf + (((size_t)(b * HH + h)) * LL) * 16;
  const unsigned char* dbase = didx8 + ((size_t)(b * LL) + row0) * LL;

  for (int ct = 0; ct < 4; ++ct) {
    const int x0 = w * 128 + ct * 32;
    bf16x8 bk0 = *(const bf16x8*)(kbase + (size_t)(x0 + lr) * QKS);
    bf16x8 bk1 = *(const bf16x8*)(kbase + (size_t)(x0 + 16 + lr) * QKS);
    int d0[4], d1[4];
    float ke0[4], ke1[4], qe0[4], qe1[4];
#pragma unroll
    for (int i = 0; i < 4; ++i) {
      const int rl = lg * 4 + i;
      const unsigned char* dr = dbase + (size_t)rl * LL + x0;
      d0[i] = dr[lr];
      d1[i] = dr[16 + lr];
    }
#pragma unroll
    for (int i = 0; i < 4; ++i) {
      ke0[i] = bf2f(kebase[(x0 + lr) * 16 + d0[i]]);
      ke1[i] = bf2f(kebase[(x0 + 16 + lr) * 16 + d1[i]]);
      const int rl = lg * 4 + i;
      qe0[i] = qEs[rl][d0[i]];
      qe1[i] = qEs[rl][d1[i]];
    }
    f32x4 s0 = __builtin_amdgcn_mfma_f32_16x16x32_bf16(aQ, bk0, zero4, 0, 0, 0);
    f32x4 s1 = __builtin_amdgcn_mfma_f32_16x16x32_bf16(aQ, bk1, zero4, 0, 0, 0);
#pragma unroll
    for (int i = 0; i < 4; ++i) {
      const int rl = lg * 4 + i;
      float p0 = __expf(s0[i] + qe0[i] + ke0[i]);
      float p1 = __expf(s1[i] + qe1[i] + ke1[i]);
      atomicAdd(&hist[w][rl][d0[i]], p0);
      atomicAdd(&hist[w][rl][d1[i]], p1);
      Pt[w][rl][lr] = f2bf(p0);
      Pt[w][rl][16 + lr] = f2bf(p1);
    }
    // per-wave LDS ordering: Pt writes drain before this read (compiler lgkmcnt)
    bf16x8 aP = *(const bf16x8*)(&Pt[w][lr][lg * 8]);
    bf16x8 vb0 = *(const bf16x8*)(vbase + (size_t)lr * LL + x0 + lg * 8);
    bf16x8 vb1 = *(const bf16x8*)(vbase + (size_t)(16 + lr) * LL + x0 + lg * 8);
    o0 = __builtin_amdgcn_mfma_f32_16x16x32_bf16(aP, vb0, o0, 0, 0, 0);
    o1 = __builtin_amdgcn_mfma_f32_16x16x32_bf16(aP, vb1, o1, 0, 0, 0);
  }

  // merge O partials across the 4 kv-split waves
#pragma unroll
  for (int i = 0; i < 4; ++i) {
    const int rl = lg * 4 + i;
    atomicAdd(&osh[rl][lr], o0[i]);
    atomicAdd(&osh[rl][16 + lr], o1[i]);
  }
  __syncthreads();

  // epilogue: thread (r, c) covers cols c and c+16 of row r; rsum = sum of hist bins
  const int r = tid >> 4, c = tid & 15;
  float ht[NDB];
  float rsum = 0.f;
#pragma unroll
  for (int d = 0; d < NDB; ++d) {
    float a = hist[0][r][d] + hist[1][r][d] + hist[2][r][d] + hist[3][r][d];
    ht[d] = a;
    rsum += a;
  }
  const float inv = 1.0f / rsum;
  float vb_0 = 0.f, vb_1 = 0.f;
#pragma unroll
  for (int d = 0; d < NDB; ++d) {
    vb_0 += ht[d] * Vsums[d][c];
    vb_1 += ht[d] * Vsums[d][16 + c];
  }
  const size_t orow = ((size_t)(b * LL + row0 + r)) * DDIM + h * KHD;
  z[orow + c] = f2bf((osh[r][c] + vb_0) * inv);
  z[orow + 16 + c] = f2bf((osh[r][16 + c] + vb_1) * inv);
}

// ---------------- out = LN(X + Y), f32 + bf16 ----------------
__global__ __launch_bounds__(256) void add_ln_kernel(
    const float* __restrict__ X, const float* __restrict__ Y,
    const float* __restrict__ g, const float* __restrict__ be,
    float* __restrict__ out, u16* __restrict__ outb) {
  const int row = blockIdx.x, tid = threadIdx.x;
  const int lane = tid & 63, wid = tid >> 6;
  __shared__ float red[4];
  const size_t base = (size_t)row * DDIM;
  float x0 = X[base + tid] + Y[base + tid];
  float x1 = X[base + tid + 256] + Y[base + tid + 256];
  float s = wredSum(x0 + x1);
  if (lane == 0) red[wid] = s;
  __syncthreads();
  float mu = (red[0] + red[1] + red[2] + red[3]) * (1.0f / DDIM);
  __syncthreads();
  float d0 = x0 - mu, d1 = x1 - mu;
  float vs = wredSum(d0 * d0 + d1 * d1);
  if (lane == 0) red[wid] = vs;
  __syncthreads();
  float var = (red[0] + red[1] + red[2] + red[3]) * (1.0f / DDIM);
  float inv = rsqrtf(var + 1e-5f);
  float r0 = d0 * inv * g[tid] + be[tid];
  float r1 = d1 * inv * g[tid + 256] + be[tid + 256];
  out[base + tid] = r0;
  out[base + tid + 256] = r1;
  outb[base + tid] = f2bf(r0);
  outb[base + tid + 256] = f2bf(r1);
}

// ---------------- pooled[b,d] = sum_l h[b,l,d] ----------------
__global__ void pool_kernel(const float* __restrict__ h, float* __restrict__ pooled, int n) {
  int i = blockIdx.x * 256 + threadIdx.x;
  if (i >= n) return;
  int b = i >> 9, d = i & 511;
  float s = 0.f;
  for (int l = 0; l < LL; ++l) s += h[(size_t)(b * LL + l) * DDIM + d];
  pooled[i] = s;
}

// ---------------- head ----------------
__global__ __launch_bounds__(256) void head_kernel(
    const float* __restrict__ pooled, const float* __restrict__ Wm1,
    const float* __restrict__ bm1, const float* __restrict__ Wm2,
    const float* __restrict__ bm2, float* __restrict__ out) {
  int b = blockIdx.x, tid = threadIdx.x;
  const float* p = pooled + b * DDIM;
  float part = 0.f;
  for (int jj = 0; jj < 2; ++jj) {
    int j = tid + jj * 256;
    float s = bm1[j];
    for (int dd = 0; dd < DDIM; ++dd) s += p[dd] * Wm1[(size_t)dd * MMD + j];
    part += fmaxf(s, 0.f) * Wm2[j];
  }
  __shared__ float red[4];
  int lane = tid & 63, wid = tid >> 6;
  float ssum = wredSum(part);
  if (lane == 0) red[wid] = ssum;
  __syncthreads();
  if (tid == 0) out[b] = red[0] + red[1] + red[2] + red[3] + bm2[0];
}

extern "C" void kernel_launch(void* const* d_in, const int* in_sizes, int n_in,
                              void* d_out, int out_size, void* d_ws, size_t ws_size,
                              hipStream_t stream) {
  const int* cell_types = (const int*)d_in[0];
  const float* distances = (const float*)d_in[1];
  const float* cell_emb = (const float*)d_in[2];
  const float* Kqk = (const float*)d_in[3];
  const float* Kqr = (const float*)d_in[4];
  const float* Kkr = (const float*)d_in[5];
  const float* Vqk = (const float*)d_in[6];
  const float* Vqr = (const float*)d_in[7];
  const float* Vkr = (const float*)d_in[8];
  const float* Wq = (const float*)d_in[9];
  const float* Wk = (const float*)d_in[10];
  const float* Wv = (const float*)d_in[11];
  const float* Wo = (const float*)d_in[12];
  const float* bq = (const float*)d_in[13];
  const float* bk = (const float*)d_in[14];
  const float* bv = (const float*)d_in[15];
  const float* bo = (const float*)d_in[16];
  const float* W1 = (const float*)d_in[17];
  const float* b1 = (const float*)d_in[18];
  const float* W2 = (const float*)d_in[19];
  const float* b2 = (const float*)d_in[20];
  const float* g1 = (const float*)d_in[21];
  const float* be1 = (const float*)d_in[22];
  const float* g2 = (const float*)d_in[23];
  const float* be2 = (const float*)d_in[24];
  const float* Wm1 = (const float*)d_in[25];
  const float* bm1 = (const float*)d_in[26];
  const float* Wm2 = (const float*)d_in[27];
  const float* bm2 = (const float*)d_in[28];

  char* w = (char*)d_ws;
  auto alloc = [&](size_t bytes) { void* p = (void*)w; w += (bytes + 255) & ~(size_t)255; return p; };
  unsigned char* didx8 = (unsigned char*)alloc(sizeof(unsigned char) * BB * LL * LL);
  float* h    = (float*)alloc(sizeof(float) * BB * LL * DDIM);
  u16* hbf    = (u16*)alloc(sizeof(u16) * BB * LL * DDIM);
  float* h2   = (float*)alloc(sizeof(float) * BB * LL * DDIM);
  u16* h2bf   = (u16*)alloc(sizeof(u16) * BB * LL * DDIM);
  u16* qkvbf  = (u16*)alloc(sizeof(u16) * BB * LL * QKS);
  float* ob   = (float*)alloc(sizeof(float) * BB * LL * DDIM);
  u16* f1bf   = (u16*)alloc(sizeof(u16) * BB * LL * FFD);
  u16* zbf    = (u16*)alloc(sizeof(u16) * BB * LL * DDIM);
  u16* vtbf   = (u16*)alloc(sizeof(u16) * BB * HH * KHD * LL);
  float* qE2  = (float*)alloc(sizeof(float) * BB * HH * LL * NDB);
  u16* kEbf   = (u16*)alloc(sizeof(u16) * (size_t)BB * HH * LL * 16);
  u16* Wqkvt  = (u16*)alloc(sizeof(u16) * QKS * DDIM);
  u16* Wot    = (u16*)alloc(sizeof(u16) * DDIM * DDIM);
  u16* W1t    = (u16*)alloc(sizeof(u16) * FFD * DDIM);
  u16* W2t    = (u16*)alloc(sizeof(u16) * DDIM * FFD);
  float* bqkv = (float*)alloc(sizeof(float) * NLAY * QKS);
  float* Vsum = (float*)alloc(sizeof(float) * NDB * KHD);
  float* EkrS = (float*)alloc(sizeof(float) * NDB);
  float* pooled = (float*)alloc(sizeof(float) * BB * DDIM);

  const int Mrows = BB * LL;

  bucketize_kernel<<<(BB * LL * LL + 255) / 256, 256, 0, stream>>>(distances, didx8, BB * LL * LL);
  embed_kernel<<<(BB * LL * DDIM + 255) / 256, 256, 0, stream>>>(cell_types, cell_emb, h, hbf, BB * LL * DDIM);
  prep_kernel<<<1, 512, 0, stream>>>(Vqk, Vqr, Vkr, Kkr, Vsum, EkrS);
  biaspack_kernel<<<(NLAY * QKS + 255) / 256, 256, 0, stream>>>(bq, bk, bv, bqkv);

  const int nrel = BB * HH * LL * NDB;

  for (int lay = 0; lay < NLAY; ++lay) {
    wconv_layer<<<768, 256, 0, stream>>>(
        Wq + (size_t)lay * DDIM * DDIM, Wk + (size_t)lay * DDIM * DDIM,
        Wv + (size_t)lay * DDIM * DDIM, Wo + (size_t)lay * DDIM * DDIM,
        W1 + (size_t)lay * DDIM * FFD, W2 + (size_t)lay * FFD * DDIM,
        Wqkvt, Wot, W1t, W2t);

    gemm_bf16<<<dim3(QKS / 128, Mrows / 64), 256, 0, stream>>>(
        hbf, Wqkvt, bqkv + (size_t)lay * QKS, nullptr, qkvbf, Mrows, QKS, DDIM, 0, 512);

    proj_relbf_kernel<<<(nrel + 255) / 256, 256, 0, stream>>>(qkvbf, Kqk, nullptr, 1.0f, qE2);
    proj_relbf16_kernel<<<(nrel + 255) / 256, 256, 0, stream>>>(qkvbf + 512, Kqr, EkrS, SCALEF, kEbf);
    vtrans_kernel<<<dim3(HH, BB), 256, 0, stream>>>(qkvbf, vtbf);
    attn4_kernel<<<dim3(32, HH, BB), 256, 0, stream>>>(qkvbf, vtbf, qE2, kEbf, didx8, Vsum, zbf);

    gemm_bf16<<<dim3(DDIM / 128, Mrows / 64), 256, 0, stream>>>(
        zbf, Wot, bo + (size_t)lay * DDIM, ob, nullptr, Mrows, DDIM, DDIM, 0, 0);
    add_ln_kernel<<<Mrows, 256, 0, stream>>>(h, ob, g1 + (size_t)lay * DDIM, be1 + (size_t)lay * DDIM, h2, h2bf);
    gemm_bf16<<<dim3(FFD / 128, Mrows / 64), 256, 0, stream>>>(
        h2bf, W1t, b1 + (size_t)lay * FFD, nullptr, f1bf, Mrows, FFD, DDIM, 1, 0);
    gemm_bf16<<<dim3(DDIM / 128, Mrows / 64), 256, 0, stream>>>(
        f1bf, W2t, b2 + (size_t)lay * DDIM, ob, nullptr, Mrows, DDIM, FFD, 0, 0);
    add_ln_kernel<<<Mrows, 256, 0, stream>>>(h2, ob, g2 + (size_t)lay * DDIM, be2 + (size_t)lay * DDIM, h, hbf);
  }

  pool_kernel<<<(BB * DDIM + 255) / 256, 256, 0, stream>>>(h, pooled, BB * DDIM);
  head_kernel<<<BB, 256, 0, stream>>>(pooled, Wm1, bm1, Wm2, bm2, (float*)d_out);
}

// Round 7
// 1827.356 us; speedup vs baseline: 1.1452x; 1.0107x over previous
//
#include <hip/hip_runtime.h>
#include <math.h>

#define NLAY 8
#define BB 4
#define LL 512
#define DDIM 512
#define HH 16
#define KHD 32
#define FFD 2048
#define MMD 512
#define NDB 14
#define QKS 1536
#define SCALEF 0.17677669529663687f

typedef unsigned short u16;
typedef unsigned int u32;
typedef __attribute__((ext_vector_type(8))) short bf16x8;
typedef __attribute__((ext_vector_type(4))) float f32x4;
typedef __attribute__((ext_vector_type(4))) u32 u32x4;

__device__ __forceinline__ u16 f2bf(float f) {
  unsigned u = __builtin_bit_cast(unsigned, f);
  u = (u + 0x7fffu + ((u >> 16) & 1u)) >> 16;
  return (u16)u;
}
__device__ __forceinline__ float bf2f(u16 v) {
  unsigned u = ((unsigned)v) << 16;
  return __builtin_bit_cast(float, u);
}
__device__ __forceinline__ u32 cvt_pk_bf16(float lo, float hi) {
  u32 r;
  asm("v_cvt_pk_bf16_f32 %0, %1, %2" : "=v"(r) : "v"(lo), "v"(hi));
  return r;
}
__device__ __forceinline__ float wredSum(float v) {
#pragma unroll
  for (int o = 32; o > 0; o >>= 1) v += __shfl_down(v, o);
  return v;
}
__device__ __forceinline__ void gload_lds16(const u16* g, u16* l) {
  __builtin_amdgcn_global_load_lds((const __attribute__((address_space(1))) void*)g,
                                   (__attribute__((address_space(3))) void*)l, 16, 0, 0);
}

// ---------------- bucketize -> uint8 ----------------
__global__ void bucketize_kernel(const float* __restrict__ dist, unsigned char* __restrict__ didx, int n) {
  int i = blockIdx.x * 256 + threadIdx.x;
  if (i >= n) return;
  float d = dist[i];
  int c = 0;
#pragma unroll
  for (int t = 1; t <= NDB; ++t) c += (10.0f * (float)t < d) ? 1 : 0;
  didx[i] = (unsigned char)(c > (NDB - 1) ? (NDB - 1) : c);
}

// ---------------- didx [b][l][x] -> didxT [b][x][l] (tiled byte transpose) ----------------
__global__ __launch_bounds__(256) void dtrans_kernel(const unsigned char* __restrict__ in,
                                                     unsigned char* __restrict__ out) {
  __shared__ unsigned char tl[64][80];
  const int x0 = blockIdx.x * 64, l0 = blockIdx.y * 64, b = blockIdx.z;
  const int t = threadIdx.x;
  {
    int r = t >> 2, c = (t & 3) * 16;
    uint4 v = *(const uint4*)(in + ((size_t)(b * LL) + l0 + r) * LL + x0 + c);
    *(uint4*)&tl[r][c] = v;
  }
  __syncthreads();
  int xr = t >> 2, c = (t & 3) * 16;
  unsigned char buf[16];
#pragma unroll
  for (int j = 0; j < 16; ++j) buf[j] = tl[c + j][xr];
  *(uint4*)(out + ((size_t)(b * LL) + x0 + xr) * LL + l0 + c) = *(uint4*)buf;
}

// ---------------- h = cell_emb[cell_types] (f32 + bf16) ----------------
__global__ void embed_kernel(const int* __restrict__ ct, const float* __restrict__ emb,
                             float* __restrict__ h, u16* __restrict__ hbf, int n) {
  int i = blockIdx.x * 256 + threadIdx.x;
  if (i >= n) return;
  int bl = i >> 9, d = i & 511;
  float v = emb[ct[bl] * DDIM + d];
  h[i] = v;
  hbf[i] = f2bf(v);
}

// ---------------- Vsum, EkrS ----------------
__global__ void prep_kernel(const float* __restrict__ Vqk, const float* __restrict__ Vqr,
                            const float* __restrict__ Vkr, const float* __restrict__ Kkr,
                            float* __restrict__ Vsum, float* __restrict__ EkrS) {
  int tid = threadIdx.x;
  if (tid < NDB * KHD) Vsum[tid] = Vqk[tid] + Vqr[tid] + Vkr[tid];
  if (tid < NDB) {
    float s = 0.f;
    for (int kk = 0; kk < KHD; ++kk) s += Kkr[tid * KHD + kk];
    EkrS[tid] = s;
  }
}

// ---------------- packed qkv bias [NLAY][1536] ----------------
__global__ void biaspack_kernel(const float* __restrict__ bq, const float* __restrict__ bk,
                                const float* __restrict__ bv, float* __restrict__ bqkv) {
  int i = blockIdx.x * 256 + threadIdx.x;
  if (i >= NLAY * QKS) return;
  int lay = i / QKS, c = i % QKS;
  float v;
  if (c < 512) v = bq[lay * DDIM + c];
  else if (c < 1024) v = bk[lay * DDIM + c - 512];
  else v = bv[lay * DDIM + c - 1024];
  bqkv[i] = v;
}

// ---------------- per-layer weight transpose+convert: src f32 [K,N] -> dst bf16 [N,K] ----------------
__device__ __forceinline__ void wtconv_tile(const float* __restrict__ src, u16* __restrict__ dst,
                                            int K, int N, int tn, int tk) {
  __shared__ float tl[64][65];
  const int t = threadIdx.x;
#pragma unroll
  for (int p = 0; p < 4; ++p) {
    int k = tk * 64 + p * 16 + (t >> 4);
    int n = tn * 64 + (t & 15) * 4;
    float4 v = *(const float4*)(src + (size_t)k * N + n);
    tl[(t & 15) * 4 + 0][p * 16 + (t >> 4)] = v.x;
    tl[(t & 15) * 4 + 1][p * 16 + (t >> 4)] = v.y;
    tl[(t & 15) * 4 + 2][p * 16 + (t >> 4)] = v.z;
    tl[(t & 15) * 4 + 3][p * 16 + (t >> 4)] = v.w;
  }
  __syncthreads();
  int n = t >> 2, cc = t & 3;
  u16 o[16];
#pragma unroll
  for (int e = 0; e < 16; ++e) o[e] = f2bf(tl[n][cc * 16 + e]);
  u16* dp = dst + (size_t)(tn * 64 + n) * K + tk * 64 + cc * 16;
  *(uint4*)(dp) = *(uint4*)&o[0];
  *(uint4*)(dp + 8) = *(uint4*)&o[8];
}

__global__ __launch_bounds__(256) void wconv_layer(
    const float* __restrict__ Wq, const float* __restrict__ Wk, const float* __restrict__ Wv,
    const float* __restrict__ Wo, const float* __restrict__ W1, const float* __restrict__ W2,
    u16* __restrict__ Wqkvt, u16* __restrict__ Wot, u16* __restrict__ W1t, u16* __restrict__ W2t) {
  int b = blockIdx.x;
  if (b < 64) { wtconv_tile(Wq, Wqkvt, 512, 512, b >> 3, b & 7); return; }
  if (b < 128) { b -= 64; wtconv_tile(Wk, Wqkvt + 512 * 512, 512, 512, b >> 3, b & 7); return; }
  if (b < 192) { b -= 128; wtconv_tile(Wv, Wqkvt + 1024 * 512, 512, 512, b >> 3, b & 7); return; }
  if (b < 256) { b -= 192; wtconv_tile(Wo, Wot, 512, 512, b >> 3, b & 7); return; }
  if (b < 512) { b -= 256; wtconv_tile(W1, W1t, 512, FFD, b >> 3, b & 7); return; }
  b -= 512; wtconv_tile(W2, W2t, FFD, 512, b >> 5, b & 31);
}

// ---------------- bf16 MFMA GEMM: C = A[M,K]bf16 @ Bt[N,K]bf16^T + bias ----------------
__global__ __launch_bounds__(256) void gemm_bf16(
    const u16* __restrict__ A, const u16* __restrict__ Bt, const float* __restrict__ bias,
    float* __restrict__ Cf, u16* __restrict__ Cb,
    int M, int N, int K, int act, int scaleLT) {
  __shared__ u16 As[64 * 64];
  __shared__ u16 Bs[128 * 64];
  const int tid = threadIdx.x, w = tid >> 6, lane = tid & 63;
  const int lr = lane & 15, lg = lane >> 4;
  const int row0 = blockIdx.y * 64, col0 = blockIdx.x * 128;
  const int srow = lane >> 3;
  const int aoff = ((lane & 7) ^ srow) * 8;
  const f32x4 z4 = {0.f, 0.f, 0.f, 0.f};
  f32x4 acc[4][2];
#pragma unroll
  for (int mi = 0; mi < 4; ++mi)
#pragma unroll
    for (int ni = 0; ni < 2; ++ni) acc[mi][ni] = z4;

  const int nw = w * 32;
  for (int k0 = 0; k0 < K; k0 += 64) {
#pragma unroll
    for (int i = 0; i < 2; ++i)
      gload_lds16(A + (size_t)(row0 + w * 16 + i * 8 + srow) * K + k0 + aoff,
                  As + (w * 16 + i * 8) * 64);
#pragma unroll
    for (int i = 0; i < 4; ++i)
      gload_lds16(Bt + (size_t)(col0 + w * 32 + i * 8 + srow) * K + k0 + aoff,
                  Bs + (w * 32 + i * 8) * 64);
    __syncthreads();
#pragma unroll
    for (int kh = 0; kh < 2; ++kh) {
      bf16x8 a[4], b[2];
#pragma unroll
      for (int mi = 0; mi < 4; ++mi) {
        int r = mi * 16 + lr;
        a[mi] = *(const bf16x8*)(As + r * 64 + (((kh * 4 + lg) ^ (r & 7)) << 3));
      }
#pragma unroll
      for (int ni = 0; ni < 2; ++ni) {
        int r = nw + ni * 16 + lr;
        b[ni] = *(const bf16x8*)(Bs + r * 64 + (((kh * 4 + lg) ^ (r & 7)) << 3));
      }
#pragma unroll
      for (int mi = 0; mi < 4; ++mi)
#pragma unroll
        for (int ni = 0; ni < 2; ++ni)
          acc[mi][ni] = __builtin_amdgcn_mfma_f32_16x16x32_bf16(a[mi], b[ni], acc[mi][ni], 0, 0, 0);
    }
    __syncthreads();
  }
#pragma unroll
  for (int mi = 0; mi < 4; ++mi) {
    int r = row0 + mi * 16 + lg * 4;
#pragma unroll
    for (int ni = 0; ni < 2; ++ni) {
      int c = col0 + nw + ni * 16 + lr;
      float bs = bias[c];
      float sc = (c < scaleLT) ? SCALEF : 1.0f;
#pragma unroll
      for (int j = 0; j < 4; ++j) {
        float v = acc[mi][ni][j] + bs;
        if (act == 1) v = 0.5f * v * (1.0f + erff(v * 0.70710678118654752f));
        size_t idx = (size_t)(r + j) * N + c;
        if (Cf) Cf[idx] = v;
        if (Cb) Cb[idx] = f2bf(v * sc);
      }
    }
  }
}

// ---------------- rel projection (f32 out, for qE) ----------------
__global__ void proj_relbf_kernel(const u16* __restrict__ x, const float* __restrict__ Kr,
                                  const float* __restrict__ ekrs, float scale_mul,
                                  float* __restrict__ outp) {
  int idx = blockIdx.x * 256 + threadIdx.x;
  if (idx >= BB * HH * LL * NDB) return;
  int d = idx % NDB;
  int rest = idx / NDB;
  int l = rest & (LL - 1);
  int bh = rest >> 9;
  int h = bh & (HH - 1);
  int b = bh >> 4;
  const u16* xr = x + ((size_t)(b * LL + l)) * QKS + h * KHD;
  const float* kr = Kr + d * KHD;
  float s = 0.f;
#pragma unroll
  for (int kk = 0; kk < KHD; ++kk) s += bf2f(xr[kk]) * kr[kk];
  s *= scale_mul;
  if (ekrs) s += SCALEF * ekrs[d];
  outp[idx] = s;
}

// ---------------- rel projection (bf16 out, [bhx][16] padded layout, for kE) ----------------
__global__ void proj_relbf16_kernel(const u16* __restrict__ x, const float* __restrict__ Kr,
                                    const float* __restrict__ ekrs, float scale_mul,
                                    u16* __restrict__ outp) {
  int idx = blockIdx.x * 256 + threadIdx.x;
  if (idx >= BB * HH * LL * NDB) return;
  int d = idx % NDB;
  int rest = idx / NDB;
  int l = rest & (LL - 1);
  int bh = rest >> 9;
  int h = bh & (HH - 1);
  int b = bh >> 4;
  const u16* xr = x + ((size_t)(b * LL + l)) * QKS + h * KHD;
  const float* kr = Kr + d * KHD;
  float s = 0.f;
#pragma unroll
  for (int kk = 0; kk < KHD; ++kk) s += bf2f(xr[kk]) * kr[kk];
  s *= scale_mul;
  if (ekrs) s += SCALEF * ekrs[d];
  outp[(size_t)rest * 16 + d] = f2bf(s);
}

// ---------------- v (packed bf16 cols 1024..1535) -> vt [b,h,kh,x] bf16 ----------------
__global__ __launch_bounds__(256) void vtrans_kernel(const u16* __restrict__ qkv, u16* __restrict__ vt) {
  const int h = blockIdx.x, b = blockIdx.y, tid = threadIdx.x;
  __shared__ u16 tile[KHD][520];
  for (int it = 0; it < 64; ++it) {
    int idx = it * 256 + tid;
    int x = idx >> 5, kh = idx & 31;
    tile[kh][x] = qkv[((size_t)(b * LL) + x) * QKS + 1024 + h * KHD + kh];
  }
  __syncthreads();
  int r = tid >> 3, seg = tid & 7;
  uint4* dst = (uint4*)(vt + ((size_t)(b * HH + h) * KHD + r) * LL);
  const uint4* src = (const uint4*)(&tile[r][0]);
#pragma unroll
  for (int j = 0; j < 8; ++j) dst[seg + j * 8] = src[seg + j * 8];
}

// ---------------- attention v5: swapped QK^T (P lane-local), in-register P -> PV ----------------
// Per block: 16 q-rows, (h,b); 4 waves kv-split 128 keys each.
// mfma(K_perm, Q): lane holds scores for q-row lr at keys x0+8*lg+{0..3} (A) / {4..7} (B),
// exactly PV's A-frag order after 4 cvt_pk -> NO LDS round-trip for P, no in-loop barriers.
// didxT gives cache-line didx gathers (16 consecutive bytes per key); kE is 1-line broadcast.
__global__ __launch_bounds__(256, 4) void attn5_kernel(
    const u16* __restrict__ qkv, const u16* __restrict__ vtbf,
    const float* __restrict__ qE2, const u16* __restrict__ kEbf,
    const unsigned char* __restrict__ didxT,
    const float* __restrict__ Vsum, u16* __restrict__ z) {
  const int qr = blockIdx.x, h = blockIdx.y, b = blockIdx.z;
  const int tid = threadIdx.x, lane = tid & 63, w = tid >> 6;
  const int lr = lane & 15, lg = lane >> 4;
  const int row0 = qr * 16;

  __shared__ float qEs[16][16];      // 1 KB padded
  __shared__ float hist[4][16][16];  // 4 KB per-wave
  __shared__ float Vsums[NDB][KHD];  // 1.8 KB
  __shared__ float osh[16][33];      // 2.1 KB

  if (tid < 224) {
    int r = tid / 14, d = tid % 14;
    qEs[r][d] = qE2[(((size_t)(b * HH + h)) * LL + row0 + r) * NDB + d];
  }
  if (tid < 112) ((float4*)Vsums)[tid] = ((const float4*)Vsum)[tid];
  if (tid < 132) ((float4*)&osh[0][0])[tid] = float4{0.f, 0.f, 0.f, 0.f};
  ((float4*)hist)[tid] = float4{0.f, 0.f, 0.f, 0.f};  // 256 float4 == whole array

  const bf16x8 aQ = *(const bf16x8*)(qkv + ((size_t)(b * LL + row0 + lr)) * QKS + h * KHD + lg * 8);

  __syncthreads();  // staging/init done — only barrier before epilogue

  f32x4 o0 = {0.f, 0.f, 0.f, 0.f}, o1 = {0.f, 0.f, 0.f, 0.f};
  const f32x4 zero4 = {0.f, 0.f, 0.f, 0.f};

  const int keyA = 8 * (lr >> 2) + (lr & 3);  // permuted K row: MFMA row r -> key 8*(r>>2)+(r&3)
  const u16* kbase = qkv + (size_t)b * LL * QKS + 512 + h * KHD + lg * 8;
  const u16* vbase = vtbf + ((size_t)(b * HH + h) * KHD) * LL;
  const u16* kebase = kEbf + (((size_t)(b * HH + h)) * LL) * 16;
  const unsigned char* dT = didxT + (size_t)b * LL * LL + row0 + lr;

#pragma unroll
  for (int ct = 0; ct < 4; ++ct) {
    const int x0 = w * 128 + ct * 32;
    bf16x8 kA = *(const bf16x8*)(kbase + (size_t)(x0 + keyA) * QKS);
    bf16x8 kB = *(const bf16x8*)(kbase + (size_t)(x0 + keyA + 4) * QKS);
    int dA[4], dB[4];
#pragma unroll
    for (int i = 0; i < 4; ++i) {
      dA[i] = dT[(size_t)(x0 + 8 * lg + i) * LL];
      dB[i] = dT[(size_t)(x0 + 8 * lg + 4 + i) * LL];
    }
    float keA[4], keB[4];
#pragma unroll
    for (int i = 0; i < 4; ++i) {
      keA[i] = bf2f(kebase[(x0 + 8 * lg + i) * 16 + dA[i]]);
      keB[i] = bf2f(kebase[(x0 + 8 * lg + 4 + i) * 16 + dB[i]]);
    }
    // swapped operands: A = K (rows=keys, permuted), B = Q (cols=q-rows)
    f32x4 sA = __builtin_amdgcn_mfma_f32_16x16x32_bf16(kA, aQ, zero4, 0, 0, 0);
    f32x4 sB = __builtin_amdgcn_mfma_f32_16x16x32_bf16(kB, aQ, zero4, 0, 0, 0);
    float pA[4], pB[4];
#pragma unroll
    for (int i = 0; i < 4; ++i) {
      pA[i] = __expf(sA[i] + qEs[lr][dA[i]] + keA[i]);
      pB[i] = __expf(sB[i] + qEs[lr][dB[i]] + keB[i]);
      atomicAdd(&hist[w][lr][dA[i]], pA[i]);
      atomicAdd(&hist[w][lr][dB[i]], pB[i]);
    }
    // pack P in-register: lane holds q-row lr, keys x0+8*lg+0..7 — exactly PV A-frag
    u32x4 pw;
    pw[0] = cvt_pk_bf16(pA[0], pA[1]);
    pw[1] = cvt_pk_bf16(pA[2], pA[3]);
    pw[2] = cvt_pk_bf16(pB[0], pB[1]);
    pw[3] = cvt_pk_bf16(pB[2], pB[3]);
    bf16x8 aP = __builtin_bit_cast(bf16x8, pw);
    bf16x8 vb0 = *(const bf16x8*)(vbase + (size_t)lr * LL + x0 + lg * 8);
    bf16x8 vb1 = *(const bf16x8*)(vbase + (size_t)(16 + lr) * LL + x0 + lg * 8);
    o0 = __builtin_amdgcn_mfma_f32_16x16x32_bf16(aP, vb0, o0, 0, 0, 0);
    o1 = __builtin_amdgcn_mfma_f32_16x16x32_bf16(aP, vb1, o1, 0, 0, 0);
  }

  // merge O partials across the 4 kv-split waves
#pragma unroll
  for (int i = 0; i < 4; ++i) {
    const int rl = lg * 4 + i;
    atomicAdd(&osh[rl][lr], o0[i]);
    atomicAdd(&osh[rl][16 + lr], o1[i]);
  }
  __syncthreads();

  // epilogue: thread (r, c) covers cols c and c+16 of row r; rsum = sum of hist bins
  const int r = tid >> 4, c = tid & 15;
  float ht[NDB];
  float rsum = 0.f;
#pragma unroll
  for (int d = 0; d < NDB; ++d) {
    float a = hist[0][r][d] + hist[1][r][d] + hist[2][r][d] + hist[3][r][d];
    ht[d] = a;
    rsum += a;
  }
  const float inv = 1.0f / rsum;
  float vb_0 = 0.f, vb_1 = 0.f;
#pragma unroll
  for (int d = 0; d < NDB; ++d) {
    vb_0 += ht[d] * Vsums[d][c];
    vb_1 += ht[d] * Vsums[d][16 + c];
  }
  const size_t orow = ((size_t)(b * LL + row0 + r)) * DDIM + h * KHD;
  z[orow + c] = f2bf((osh[r][c] + vb_0) * inv);
  z[orow + 16 + c] = f2bf((osh[r][16 + c] + vb_1) * inv);
}

// ---------------- out = LN(X + Y), f32 + bf16 ----------------
__global__ __launch_bounds__(256) void add_ln_kernel(
    const float* __restrict__ X, const float* __restrict__ Y,
    const float* __restrict__ g, const float* __restrict__ be,
    float* __restrict__ out, u16* __restrict__ outb) {
  const int row = blockIdx.x, tid = threadIdx.x;
  const int lane = tid & 63, wid = tid >> 6;
  __shared__ float red[4];
  const size_t base = (size_t)row * DDIM;
  float x0 = X[base + tid] + Y[base + tid];
  float x1 = X[base + tid + 256] + Y[base + tid + 256];
  float s = wredSum(x0 + x1);
  if (lane == 0) red[wid] = s;
  __syncthreads();
  float mu = (red[0] + red[1] + red[2] + red[3]) * (1.0f / DDIM);
  __syncthreads();
  float d0 = x0 - mu, d1 = x1 - mu;
  float vs = wredSum(d0 * d0 + d1 * d1);
  if (lane == 0) red[wid] = vs;
  __syncthreads();
  float var = (red[0] + red[1] + red[2] + red[3]) * (1.0f / DDIM);
  float inv = rsqrtf(var + 1e-5f);
  float r0 = d0 * inv * g[tid] + be[tid];
  float r1 = d1 * inv * g[tid + 256] + be[tid + 256];
  out[base + tid] = r0;
  out[base + tid + 256] = r1;
  outb[base + tid] = f2bf(r0);
  outb[base + tid + 256] = f2bf(r1);
}

// ---------------- pooled[b,d] = sum_l h[b,l,d] ----------------
__global__ void pool_kernel(const float* __restrict__ h, float* __restrict__ pooled, int n) {
  int i = blockIdx.x * 256 + threadIdx.x;
  if (i >= n) return;
  int b = i >> 9, d = i & 511;
  float s = 0.f;
  for (int l = 0; l < LL; ++l) s += h[(size_t)(b * LL + l) * DDIM + d];
  pooled[i] = s;
}

// ---------------- head ----------------
__global__ __launch_bounds__(256) void head_kernel(
    const float* __restrict__ pooled, const float* __restrict__ Wm1,
    const float* __restrict__ bm1, const float* __restrict__ Wm2,
    const float* __restrict__ bm2, float* __restrict__ out) {
  int b = blockIdx.x, tid = threadIdx.x;
  const float* p = pooled + b * DDIM;
  float part = 0.f;
  for (int jj = 0; jj < 2; ++jj) {
    int j = tid + jj * 256;
    float s = bm1[j];
    for (int dd = 0; dd < DDIM; ++dd) s += p[dd] * Wm1[(size_t)dd * MMD + j];
    part += fmaxf(s, 0.f) * Wm2[j];
  }
  __shared__ float red[4];
  int lane = tid & 63, wid = tid >> 6;
  float ssum = wredSum(part);
  if (lane == 0) red[wid] = ssum;
  __syncthreads();
  if (tid == 0) out[b] = red[0] + red[1] + red[2] + red[3] + bm2[0];
}

extern "C" void kernel_launch(void* const* d_in, const int* in_sizes, int n_in,
                              void* d_out, int out_size, void* d_ws, size_t ws_size,
                              hipStream_t stream) {
  const int* cell_types = (const int*)d_in[0];
  const float* distances = (const float*)d_in[1];
  const float* cell_emb = (const float*)d_in[2];
  const float* Kqk = (const float*)d_in[3];
  const float* Kqr = (const float*)d_in[4];
  const float* Kkr = (const float*)d_in[5];
  const float* Vqk = (const float*)d_in[6];
  const float* Vqr = (const float*)d_in[7];
  const float* Vkr = (const float*)d_in[8];
  const float* Wq = (const float*)d_in[9];
  const float* Wk = (const float*)d_in[10];
  const float* Wv = (const float*)d_in[11];
  const float* Wo = (const float*)d_in[12];
  const float* bq = (const float*)d_in[13];
  const float* bk = (const float*)d_in[14];
  const float* bv = (const float*)d_in[15];
  const float* bo = (const float*)d_in[16];
  const float* W1 = (const float*)d_in[17];
  const float* b1 = (const float*)d_in[18];
  const float* W2 = (const float*)d_in[19];
  const float* b2 = (const float*)d_in[20];
  const float* g1 = (const float*)d_in[21];
  const float* be1 = (const float*)d_in[22];
  const float* g2 = (const float*)d_in[23];
  const float* be2 = (const float*)d_in[24];
  const float* Wm1 = (const float*)d_in[25];
  const float* bm1 = (const float*)d_in[26];
  const float* Wm2 = (const float*)d_in[27];
  const float* bm2 = (const float*)d_in[28];

  char* w = (char*)d_ws;
  auto alloc = [&](size_t bytes) { void* p = (void*)w; w += (bytes + 255) & ~(size_t)255; return p; };
  unsigned char* didx8 = (unsigned char*)alloc(sizeof(unsigned char) * BB * LL * LL);
  unsigned char* didxT = (unsigned char*)alloc(sizeof(unsigned char) * BB * LL * LL);
  float* h    = (float*)alloc(sizeof(float) * BB * LL * DDIM);
  u16* hbf    = (u16*)alloc(sizeof(u16) * BB * LL * DDIM);
  float* h2   = (float*)alloc(sizeof(float) * BB * LL * DDIM);
  u16* h2bf   = (u16*)alloc(sizeof(u16) * BB * LL * DDIM);
  u16* qkvbf  = (u16*)alloc(sizeof(u16) * BB * LL * QKS);
  float* ob   = (float*)alloc(sizeof(float) * BB * LL * DDIM);
  u16* f1bf   = (u16*)alloc(sizeof(u16) * BB * LL * FFD);
  u16* zbf    = (u16*)alloc(sizeof(u16) * BB * LL * DDIM);
  u16* vtbf   = (u16*)alloc(sizeof(u16) * BB * HH * KHD * LL);
  float* qE2  = (float*)alloc(sizeof(float) * BB * HH * LL * NDB);
  u16* kEbf   = (u16*)alloc(sizeof(u16) * (size_t)BB * HH * LL * 16);
  u16* Wqkvt  = (u16*)alloc(sizeof(u16) * QKS * DDIM);
  u16* Wot    = (u16*)alloc(sizeof(u16) * DDIM * DDIM);
  u16* W1t    = (u16*)alloc(sizeof(u16) * FFD * DDIM);
  u16* W2t    = (u16*)alloc(sizeof(u16) * DDIM * FFD);
  float* bqkv = (float*)alloc(sizeof(float) * NLAY * QKS);
  float* Vsum = (float*)alloc(sizeof(float) * NDB * KHD);
  float* EkrS = (float*)alloc(sizeof(float) * NDB);
  float* pooled = (float*)alloc(sizeof(float) * BB * DDIM);

  const int Mrows = BB * LL;

  bucketize_kernel<<<(BB * LL * LL + 255) / 256, 256, 0, stream>>>(distances, didx8, BB * LL * LL);
  dtrans_kernel<<<dim3(8, 8, BB), 256, 0, stream>>>(didx8, didxT);
  embed_kernel<<<(BB * LL * DDIM + 255) / 256, 256, 0, stream>>>(cell_types, cell_emb, h, hbf, BB * LL * DDIM);
  prep_kernel<<<1, 512, 0, stream>>>(Vqk, Vqr, Vkr, Kkr, Vsum, EkrS);
  biaspack_kernel<<<(NLAY * QKS + 255) / 256, 256, 0, stream>>>(bq, bk, bv, bqkv);

  const int nrel = BB * HH * LL * NDB;

  for (int lay = 0; lay < NLAY; ++lay) {
    wconv_layer<<<768, 256, 0, stream>>>(
        Wq + (size_t)lay * DDIM * DDIM, Wk + (size_t)lay * DDIM * DDIM,
        Wv + (size_t)lay * DDIM * DDIM, Wo + (size_t)lay * DDIM * DDIM,
        W1 + (size_t)lay * DDIM * FFD, W2 + (size_t)lay * FFD * DDIM,
        Wqkvt, Wot, W1t, W2t);

    gemm_bf16<<<dim3(QKS / 128, Mrows / 64), 256, 0, stream>>>(
        hbf, Wqkvt, bqkv + (size_t)lay * QKS, nullptr, qkvbf, Mrows, QKS, DDIM, 0, 512);

    proj_relbf_kernel<<<(nrel + 255) / 256, 256, 0, stream>>>(qkvbf, Kqk, nullptr, 1.0f, qE2);
    proj_relbf16_kernel<<<(nrel + 255) / 256, 256, 0, stream>>>(qkvbf + 512, Kqr, EkrS, SCALEF, kEbf);
    vtrans_kernel<<<dim3(HH, BB), 256, 0, stream>>>(qkvbf, vtbf);
    attn5_kernel<<<dim3(32, HH, BB), 256, 0, stream>>>(qkvbf, vtbf, qE2, kEbf, didxT, Vsum, zbf);

    gemm_bf16<<<dim3(DDIM / 128, Mrows / 64), 256, 0, stream>>>(
        zbf, Wot, bo + (size_t)lay * DDIM, ob, nullptr, Mrows, DDIM, DDIM, 0, 0);
    add_ln_kernel<<<Mrows, 256, 0, stream>>>(h, ob, g1 + (size_t)lay * DDIM, be1 + (size_t)lay * DDIM, h2, h2bf);
    gemm_bf16<<<dim3(FFD / 128, Mrows / 64), 256, 0, stream>>>(
        h2bf, W1t, b1 + (size_t)lay * FFD, nullptr, f1bf, Mrows, FFD, DDIM, 1, 0);
    gemm_bf16<<<dim3(DDIM / 128, Mrows / 64), 256, 0, stream>>>(
        f1bf, W2t, b2 + (size_t)lay * DDIM, ob, nullptr, Mrows, DDIM, FFD, 0, 0);
    add_ln_kernel<<<Mrows, 256, 0, stream>>>(h2, ob, g2 + (size_t)lay * DDIM, be2 + (size_t)lay * DDIM, h, hbf);
  }

  pool_kernel<<<(BB * DDIM + 255) / 256, 256, 0, stream>>>(h, pooled, BB * DDIM);
  head_kernel<<<BB, 256, 0, stream>>>(pooled, Wm1, bm1, Wm2, bm2, (float*)d_out);
}